// Round 12
// baseline (499.623 us; speedup 1.0000x reference)
//
#include <hip/hip_runtime.h>
#include <math.h>

#define N_NODES 20000
#define E_HALF  160000
#define E_DIR   320000
#define IN_C    512
#define HID     128
#define OUTC    40

typedef unsigned short u16;
typedef unsigned int   u32;
typedef __attribute__((ext_vector_type(8))) short short8;   // 8 bf16
typedef __attribute__((ext_vector_type(4))) float f32x4;

// f32 weight arena offsets (elements)
#define OFF_WIN1  0
#define OFF_BIN1  32768
#define OFF_WIN2  32832
#define OFF_BIN2  41024
#define OFF_WMAP1 41152
#define OFF_BMAP1 57536
#define OFF_WMAP2 57600
#define OFF_BMAP2 57856
#define OFF_WOUT1 57860
#define OFF_BOUT1 66052
#define OFF_WOUT2 66116
#define OFF_BOUT2 68676
#define OFF_W1_0  68716
#define OFF_W2_0  68720
#define OFF_W1_1  72816
#define OFF_W2_1  72820
#define WTOTAL    76916
// transposed (k-major) copies
#define OFF_W1T     76916
#define OFF_WIN2T   109684
#define OFF_WMAP1AT 117876
#define OFF_WMAP1BT 126068
#define OFF_W2_0T   134260
#define OFF_W2_1T   138356
#define OFF_WOUT1T  142452
#define TTOTAL      73728
// MFMA B-fragment swizzled w_in1 hi/lo (u16 each, BSW_N entries)
#define OFF_BSWH  150656
#define OFF_BSWL  167040
#define BSW_N     32768

__device__ __forceinline__ float bfu2f(u16 u) {
  union { u32 i; float f; } v; v.i = ((u32)u) << 16; return v.f;
}
__device__ __forceinline__ u16 f2bf(float f) {
  union { float f; u32 u; } v; v.f = f;
  u32 u = v.u;
  u += 0x7fffu + ((u >> 16) & 1u);   // RNE
  return (u16)(u >> 16);
}

// ---- K0: sniff input float dtype. flag=1 -> bf16, flag=0 -> f32 ------------
__global__ void k_sniff(const u16* __restrict__ xv, int* __restrict__ flag) {
  __shared__ int s_bad;
  if (threadIdx.x == 0) s_bad = 0;
  __syncthreads();
  int bad = 0;
  for (int i = threadIdx.x; i < 2048; i += 256) {
    u16 u = xv[i];
    u32 ex = (u >> 7) & 0xFFu;
    if (!(ex >= 100 && ex <= 140) && (u & 0x7FFFu) != 0) bad++;
  }
  atomicAdd(&s_bad, bad);
  __syncthreads();
  if (threadIdx.x == 0) *flag = (s_bad < 64) ? 1 : 0;
}

// ---- K0b: convert weights + k-major transposes + MFMA B-swizzle hi/lo ------
struct P16 { const void* p[16]; };
__device__ __forceinline__ float rd_src(const void* p, int idx, int bf) {
  if (bf) return bfu2f(((const u16*)p)[idx]);
  return ((const float*)p)[idx];
}
__global__ __launch_bounds__(256) void k_convert(P16 s, const int* __restrict__ flag,
                                                 float* __restrict__ dst) {
  const int offs[17] = {OFF_WIN1, OFF_BIN1, OFF_WIN2, OFF_BIN2, OFF_WMAP1,
                        OFF_BMAP1, OFF_WMAP2, OFF_BMAP2, OFF_WOUT1, OFF_BOUT1,
                        OFF_WOUT2, OFF_BOUT2, OFF_W1_0, OFF_W2_0, OFF_W1_1,
                        OFF_W2_1, WTOTAL};
  const int i = blockIdx.x * 256 + threadIdx.x;
  const int bf = *flag;
  if (i < WTOTAL) {
    int sg = 0;
    #pragma unroll
    for (int k = 1; k < 16; ++k) if (i >= offs[k]) sg = k;
    dst[i] = rd_src(s.p[sg], i - offs[sg], bf);
    return;
  }
  if (i < WTOTAL + TTOTAL) {
    const int it = i - WTOTAL;
    // {dst_off, Pidx, J, src_stride, size, colofs}
    const int tab[7][6] = {
      {OFF_W1T,      0, 64, 512, 32768,   0},
      {OFF_WIN2T,    2, 128, 64,  8192,   0},
      {OFF_WMAP1AT,  4, 64, 256,  8192,   0},
      {OFF_WMAP1BT,  4, 64, 256,  8192, 128},
      {OFF_W2_0T,   13, 64,  64,  4096,   0},
      {OFF_W2_1T,   15, 64,  64,  4096,   0},
      {OFF_WOUT1T,   8, 64, 128,  8192,   0}};
    int sg = 0, base = 0;
    #pragma unroll
    for (int t = 0; t < 7; ++t) {
      if (it >= base && it < base + tab[t][4]) { sg = t; break; }
      base += tab[t][4];
    }
    const int local = it - base;
    const int J = tab[sg][2];
    const int k = local / J, j = local - k * J;
    dst[tab[sg][0] + local] =
        rd_src(s.p[tab[sg][1]], j * tab[sg][3] + k + tab[sg][5], bf);
    return;
  }
  const int ib = i - (WTOTAL + TTOTAL);
  if (ib >= 2 * BSW_N) return;
  const int which = ib >> 15;                 // 0 = hi, 1 = lo
  const int ic = ib & (BSW_N - 1);
  // B-fragment swizzle of w_in1 for mfma_f32_16x16x32_bf16:
  // lane l holds B[k=(l>>4)*8+j][n=l&15]; buffer idx ((kc*4+nt)*64+l)*8+j
  const int j = ic & 7, l = (ic >> 3) & 63, nt = (ic >> 9) & 3, kc = ic >> 11;
  const int col = nt * 16 + (l & 15);         // output channel (0..63)
  const int kk = kc * 32 + (l >> 4) * 8 + j;  // k index (0..511)
  u16 outv;
  if (bf) {
    u16 wv = ((const u16*)s.p[0])[col * 512 + kk];
    outv = which ? (u16)0 : wv;
  } else {
    float wv = ((const float*)s.p[0])[col * 512 + kk];
    u16 hi = f2bf(wv);
    if (which == 0) outv = hi;
    else            outv = f2bf(wv - bfu2f(hi));
  }
  ((u16*)(dst + (which ? OFF_BSWL : OFF_BSWH)))[ic] = outv;
}

// ---- K0c: degree histogram (needs only ei) ---------------------------------
__global__ __launch_bounds__(256) void k_deg(const int* __restrict__ ei,
                                             int* __restrict__ deg) {
  const int e = blockIdx.x * 256 + threadIdx.x;
  if (e < E_DIR) atomicAdd(&deg[ei[e]], 1);
}

// ---- K1: h = MLP_in(x) + fused u_s/u_d (bf16 out).  Wave-parallel, MFMA ----
__global__ __launch_bounds__(256) void k_mlp_in(
    const void* __restrict__ xv, const int* __restrict__ flag,
    const float* __restrict__ wf, const u16* __restrict__ bswh,
    const u16* __restrict__ bswl,
    float* __restrict__ h, u16* __restrict__ u_s16, u16* __restrict__ u_d16)
{
  __shared__ float smem[12800];
  const int t = threadIdx.x;
  const int w = t >> 6, l = t & 63;
  const int nw = blockIdx.x * 64 + w * 16;    // wave's node base
  if (nw >= N_NODES) return;                  // wave-uniform (N % 16 == 0)
  const int bf = *flag;
  const int m = l & 15, q = l >> 4;
  float (*sh)[68]   = (float(*)[68])(smem + w * 1088);           // 16x68
  float (*hti)[132] = (float(*)[132])(smem + 4352 + w * 2112);   // 16x132

  // ---- layer1: [16x512] @ [512x64] via MFMA -------------------------------
  {
    f32x4 acc0 = {0.f,0.f,0.f,0.f}, acc1 = acc0, acc2 = acc0, acc3 = acc0;
    for (int kc = 0; kc < 16; ++kc) {
      short8 Ahi = (short8)0, Alo = (short8)0;
      if (bf) {
        Ahi = *(const short8*)((const u16*)xv + (size_t)(nw + m) * IN_C + kc * 32 + q * 8);
      } else {
        const float* xr = (const float*)xv + (size_t)(nw + m) * IN_C + kc * 32 + q * 8;
        float4 xa = *(const float4*)xr;
        float4 xb = *(const float4*)(xr + 4);
        float xf[8] = {xa.x, xa.y, xa.z, xa.w, xb.x, xb.y, xb.z, xb.w};
        #pragma unroll
        for (int j = 0; j < 8; ++j) {
          u16 hi = f2bf(xf[j]);
          union { float f; u32 u; } rv; rv.f = xf[j] - bfu2f(hi);
          Ahi[j] = (short)hi;
          Alo[j] = (short)(rv.u >> 16);       // trunc bf16 of residual
        }
      }
      const u16* bh = bswh + (size_t)(kc * 4) * 512 + l * 8;
      short8 B0 = *(const short8*)(bh);
      short8 B1 = *(const short8*)(bh + 512);
      short8 B2 = *(const short8*)(bh + 1024);
      short8 B3 = *(const short8*)(bh + 1536);
      if (!bf) {
        const u16* bl = bswl + (size_t)(kc * 4) * 512 + l * 8;
        short8 L0 = *(const short8*)(bl);
        short8 L1 = *(const short8*)(bl + 512);
        short8 L2 = *(const short8*)(bl + 1024);
        short8 L3 = *(const short8*)(bl + 1536);
        acc0 = __builtin_amdgcn_mfma_f32_16x16x32_bf16(Alo, B0, acc0, 0, 0, 0);
        acc1 = __builtin_amdgcn_mfma_f32_16x16x32_bf16(Alo, B1, acc1, 0, 0, 0);
        acc2 = __builtin_amdgcn_mfma_f32_16x16x32_bf16(Alo, B2, acc2, 0, 0, 0);
        acc3 = __builtin_amdgcn_mfma_f32_16x16x32_bf16(Alo, B3, acc3, 0, 0, 0);
        acc0 = __builtin_amdgcn_mfma_f32_16x16x32_bf16(Ahi, L0, acc0, 0, 0, 0);
        acc1 = __builtin_amdgcn_mfma_f32_16x16x32_bf16(Ahi, L1, acc1, 0, 0, 0);
        acc2 = __builtin_amdgcn_mfma_f32_16x16x32_bf16(Ahi, L2, acc2, 0, 0, 0);
        acc3 = __builtin_amdgcn_mfma_f32_16x16x32_bf16(Ahi, L3, acc3, 0, 0, 0);
      }
      acc0 = __builtin_amdgcn_mfma_f32_16x16x32_bf16(Ahi, B0, acc0, 0, 0, 0);
      acc1 = __builtin_amdgcn_mfma_f32_16x16x32_bf16(Ahi, B1, acc1, 0, 0, 0);
      acc2 = __builtin_amdgcn_mfma_f32_16x16x32_bf16(Ahi, B2, acc2, 0, 0, 0);
      acc3 = __builtin_amdgcn_mfma_f32_16x16x32_bf16(Ahi, B3, acc3, 0, 0, 0);
    }
    f32x4 av[4] = {acc0, acc1, acc2, acc3};
    #pragma unroll
    for (int nt = 0; nt < 4; ++nt) {
      const int j = nt * 16 + m;
      const float bj = wf[OFF_BIN1 + j];
      #pragma unroll
      for (int r = 0; r < 4; ++r)
        sh[q * 4 + r][j] = fmaxf(av[nt][r] + bj, 0.f);
    }
  }
  // ---- layer2: [16x64] @ [64x128] f32 VALU; lanes: 4 nodes x 8 outputs ----
  {
    const int ngrp = l >> 4, og = (l & 15) * 8;
    f32x4 a2a[4], a2b[4];
    #pragma unroll
    for (int i = 0; i < 4; ++i) { a2a[i] = (f32x4){0.f,0.f,0.f,0.f}; a2b[i] = a2a[i]; }
    for (int k = 0; k < 64; k += 4) {
      f32x4 sv[4], w0[4], w1[4];
      #pragma unroll
      for (int i = 0; i < 4; ++i) sv[i] = *(f32x4*)&sh[ngrp * 4 + i][k];
      #pragma unroll
      for (int kk = 0; kk < 4; ++kk) {
        const float* wr = wf + OFF_WIN2T + (k + kk) * 128 + og;
        w0[kk] = *(const f32x4*)wr;
        w1[kk] = *(const f32x4*)(wr + 4);
      }
      #pragma unroll
      for (int i = 0; i < 4; ++i) {
        #pragma unroll
        for (int kk = 0; kk < 4; ++kk) {
          a2a[i] += sv[i][kk] * w0[kk];
          a2b[i] += sv[i][kk] * w1[kk];
        }
      }
    }
    f32x4 b2a = *(const f32x4*)(wf + OFF_BIN2 + og);
    f32x4 b2b = *(const f32x4*)(wf + OFF_BIN2 + og + 4);
    #pragma unroll
    for (int i = 0; i < 4; ++i) {
      a2a[i] += b2a; a2b[i] += b2b;
      const int node = nw + ngrp * 4 + i;
      *(f32x4*)&h[(size_t)node * HID + og]     = a2a[i];
      *(f32x4*)&h[(size_t)node * HID + og + 4] = a2b[i];
      *(f32x4*)&hti[ngrp * 4 + i][og]     = a2a[i];
      *(f32x4*)&hti[ngrp * 4 + i][og + 4] = a2b[i];
    }
  }
  // ---- u-projection: [16x128] @ [128x64] x2 -> bf16 stores ----------------
  {
    const int ngrp = l >> 4, ug = (l & 15) * 4;
    f32x4 us[4], ud[4];
    #pragma unroll
    for (int i = 0; i < 4; ++i) { us[i] = (f32x4){0.f,0.f,0.f,0.f}; ud[i] = us[i]; }
    for (int k = 0; k < 128; k += 4) {
      f32x4 av[4], wsv[4], wdv[4];
      #pragma unroll
      for (int i = 0; i < 4; ++i) av[i] = *(f32x4*)&hti[ngrp * 4 + i][k];
      #pragma unroll
      for (int kk = 0; kk < 4; ++kk) {
        wsv[kk] = *(const f32x4*)(wf + OFF_WMAP1AT + (k + kk) * 64 + ug);
        wdv[kk] = *(const f32x4*)(wf + OFF_WMAP1BT + (k + kk) * 64 + ug);
      }
      #pragma unroll
      for (int i = 0; i < 4; ++i) {
        #pragma unroll
        for (int kk = 0; kk < 4; ++kk) {
          us[i] += av[i][kk] * wsv[kk];
          ud[i] += av[i][kk] * wdv[kk];
        }
      }
    }
    #pragma unroll
    for (int i = 0; i < 4; ++i) {
      const int node = nw + ngrp * 4 + i;
      ushort4 os, od;
      os.x = f2bf(us[i][0]); os.y = f2bf(us[i][1]);
      os.z = f2bf(us[i][2]); os.w = f2bf(us[i][3]);
      od.x = f2bf(ud[i][0]); od.y = f2bf(ud[i][1]);
      od.z = f2bf(ud[i][2]); od.w = f2bf(ud[i][3]);
      *(ushort4*)&u_s16[(size_t)node * 64 + ug] = os;
      *(ushort4*)&u_d16[(size_t)node * 64 + ug] = od;
    }
  }
}

// ---- K2: edge maps, CSR-ordered; maps written in CSR slot order ------------
__global__ __launch_bounds__(256) void k_edge_maps_csr(
    const u16* __restrict__ u_s16, const u16* __restrict__ u_d16,
    const int* __restrict__ ei, const int* __restrict__ csr_eid,
    const float* __restrict__ wf, float* __restrict__ maps)
{
  __shared__ float s_act[64][68];
  const int t = threadIdx.x;
  const int w = t >> 6, l = t & 63;
  const int p0 = blockIdx.x * 64;
  const float bias = wf[OFF_BMAP1 + l];
  const int pb = p0 + w * 16;
  #pragma unroll 4
  for (int i = 0; i < 16; ++i) {
    const int e = csr_eid[pb + i];
    const int sn = ei[e], dn = ei[E_DIR + e];
    float v = bfu2f(u_s16[(size_t)sn * 64 + l]) +
              bfu2f(u_d16[(size_t)dn * 64 + l]) + bias;
    s_act[w * 16 + i][l] = fmaxf(v, 0.f);
  }
  __syncthreads();
  const int ee = t >> 2, ko = t & 3;
  float acc = wf[OFF_BMAP2 + ko];
  const float* wr = wf + OFF_WMAP2 + ko * 64;
  #pragma unroll
  for (int j = 0; j < 64; j += 4) {
    float4 wv = *(const float4*)(wr + j);
    float4 av = *(const float4*)(&s_act[ee][j]);
    acc += av.x*wv.x + av.y*wv.y + av.z*wv.z + av.w*wv.w;
  }
  maps[(p0 + ee) * 4 + ko] = acc;
}

// ---- K4b: exclusive scan of deg -> offsets (+cursor copy), 1 block ---------
__global__ __launch_bounds__(256) void k_scan(
    const int* __restrict__ deg, int* __restrict__ offsets,
    int* __restrict__ cursor)
{
  __shared__ int s[256];
  const int t = threadIdx.x;
  const int c0 = t * 79;
  int sum = 0;
  for (int i = 0; i < 79; ++i) {
    int idx = c0 + i;
    if (idx < N_NODES) sum += deg[idx];
  }
  s[t] = sum;
  __syncthreads();
  int run = sum;
  for (int off = 1; off < 256; off <<= 1) {
    int tmp = (t >= off) ? s[t - off] : 0;
    __syncthreads();
    s[t] += tmp;
    __syncthreads();
  }
  int base = s[t] - run;
  for (int i = 0; i < 79; ++i) {
    int idx = c0 + i;
    if (idx < N_NODES) {
      offsets[idx] = base;
      cursor[idx] = base;
      base += deg[idx];
    }
  }
  if (t == 255) offsets[N_NODES] = E_DIR;
}

// ---- K4c: bucket edges by src; record slot of each edge --------------------
__global__ __launch_bounds__(256) void k_csr_build(
    const int* __restrict__ ei, int* __restrict__ cursor,
    int* __restrict__ csr_eid, int* __restrict__ eslot)
{
  const int e = blockIdx.x * 256 + threadIdx.x;
  if (e >= E_DIR) return;
  const int sn = ei[e];
  const int pos = atomicAdd(&cursor[sn], 1);
  csr_eid[pos] = e;
  eslot[e] = pos;
}

// ---- K4d: per-node FtF gather (sequential CSR maps) + 2x2 eig --------------
__global__ __launch_bounds__(256) void k_ftf_norm(
    const float* __restrict__ maps, const int* __restrict__ offsets,
    float* __restrict__ Dinv, float* __restrict__ diag_n)
{
  const int n = blockIdx.x * 256 + threadIdx.x;
  if (n >= N_NODES) return;
  const int s = offsets[n], e = offsets[n + 1];
  float a = 0.f, b = 0.f, c = 0.f;
  for (int p = s; p < e; ++p) {
    float4 m = *(const float4*)(maps + (size_t)p * 4);
    a += m.x * m.x + m.z * m.z;
    b += m.x * m.y + m.z * m.w;
    c += m.y * m.y + m.w * m.w;
  }
  float mean = 0.5f * (a + c), diff = 0.5f * (a - c);
  float rad = sqrtf(diff * diff + b * b);
  float l1 = mean - rad, l2 = mean + rad;
  float s1 = 1.0f / sqrtf(fmaxf(l1, 1e-6f));
  float s2 = 1.0f / sqrtf(fmaxf(l2, 1e-6f));
  float D00, D01, D11;
  if (rad < 1e-20f) {
    float s0 = 1.0f / sqrtf(fmaxf(mean, 1e-6f));
    D00 = s0; D01 = 0.f; D11 = s0;
  } else {
    float vx, vy;
    if (diff >= 0.f) { vx = rad + diff; vy = b; }
    else             { vx = b;          vy = rad - diff; }
    float inv = 1.0f / sqrtf(vx * vx + vy * vy);
    float ux = vx * inv, uy = vy * inv;
    D00 = s1 * uy * uy + s2 * ux * ux;
    D01 = (s2 - s1) * ux * uy;
    D11 = s1 * ux * ux + s2 * uy * uy;
  }
  Dinv[n * 4 + 0] = D00; Dinv[n * 4 + 1] = D01;
  Dinv[n * 4 + 2] = D01; Dinv[n * 4 + 3] = D11;
  float t00 = D00 * a + D01 * b, t01 = D00 * b + D01 * c;
  float t10 = D01 * a + D11 * b, t11 = D01 * b + D11 * c;
  diag_n[n * 4 + 0] = t00 * D00 + t01 * D01;
  diag_n[n * 4 + 1] = t00 * D01 + t01 * D11;
  diag_n[n * 4 + 2] = t10 * D00 + t11 * D01;
  diag_n[n * 4 + 3] = t10 * D01 + t11 * D11;
}

// ---- K5: off_n per CSR position (coalesced maps/csr writes) ----------------
__global__ void k_offn2(const float* __restrict__ maps, const int* __restrict__ ei,
                        const float* __restrict__ Dinv, const int* __restrict__ eslot,
                        const int* __restrict__ csr_eid,
                        int* __restrict__ csr_dst, float4* __restrict__ csr_off)
{
  const int pos = blockIdx.x * 256 + threadIdx.x;
  if (pos >= E_DIR) return;
  const int e = csr_eid[pos];
  const int r = (e < E_HALF) ? (e + E_HALF) : (e - E_HALF);
  const int rpos = eslot[r];
  float4 me = *(const float4*)(maps + (size_t)pos * 4);
  float4 mr = *(const float4*)(maps + (size_t)rpos * 4);
  float o00 = -(me.x * mr.x + me.z * mr.z);
  float o01 = -(me.x * mr.y + me.z * mr.w);
  float o10 = -(me.y * mr.x + me.w * mr.z);
  float o11 = -(me.y * mr.y + me.w * mr.w);
  const int sn = ei[e], dn = ei[E_DIR + e];
  float4 Ds = *(const float4*)(Dinv + sn * 4);
  float4 Dd = *(const float4*)(Dinv + dn * 4);
  float t00 = Ds.x * o00 + Ds.y * o10;
  float t01 = Ds.x * o01 + Ds.y * o11;
  float t10 = Ds.z * o00 + Ds.w * o10;
  float t11 = Ds.z * o01 + Ds.w * o11;
  float4 q;
  q.x = t00 * Dd.x + t01 * Dd.z;
  q.y = t00 * Dd.y + t01 * Dd.w;
  q.z = t10 * Dd.x + t11 * Dd.z;
  q.w = t10 * Dd.y + t11 * Dd.w;
  csr_dst[pos] = dn;
  csr_off[pos] = q;
}

// ---- K6a: Ht = W1^T (h3 @ W2^T) per node -----------------------------------
__global__ __launch_bounds__(256) void k_ht(
    const float* __restrict__ h, const float* __restrict__ wf,
    int offW1, int offW2T, float* __restrict__ Ht)
{
  const int t = threadIdx.x;
  const int n = blockIdx.x * 4 + (t >> 6);
  const int g = t & 63;
  const float w1_00 = wf[offW1 + 0], w1_01 = wf[offW1 + 1];
  const float w1_10 = wf[offW1 + 2], w1_11 = wf[offW1 + 3];
  float acc0 = 0.f, acc1 = 0.f;
  const float* wt = wf + offW2T + g;
  const float* h0 = h + (size_t)n * HID;
  #pragma unroll 4
  for (int kk = 0; kk < 64; kk += 4) {
    float4 p0 = *(const float4*)(h0 + kk);
    float4 p1 = *(const float4*)(h0 + 64 + kk);
    const float* w0 = wt + kk * 64;
    float wv0 = w0[0], wv1 = w0[64], wv2 = w0[128], wv3 = w0[192];
    acc0 += p0.x*wv0 + p0.y*wv1 + p0.z*wv2 + p0.w*wv3;
    acc1 += p1.x*wv0 + p1.y*wv1 + p1.z*wv2 + p1.w*wv3;
  }
  Ht[n * HID + g]      = w1_00 * acc0 + w1_10 * acc1;
  Ht[n * HID + 64 + g] = w1_01 * acc0 + w1_11 * acc1;
}

// ---- K6b: per-node gather msgs + diag term + ELU + h update (fused) --------
__global__ __launch_bounds__(256) void k_msgs_fused(
    const int* __restrict__ offsets, const int* __restrict__ csr_dst,
    const float4* __restrict__ csr_off, const float* __restrict__ diag_n,
    const float* __restrict__ Ht, float* __restrict__ h)
{
  const int n = blockIdx.x * 4 + (threadIdx.x >> 6);
  const int g = threadIdx.x & 63;
  const int s = offsets[n], e = offsets[n + 1];
  float acc0 = 0.f, acc1 = 0.f;
  int d_next = (s < e) ? csr_dst[s] : 0;
  float4 o_next = (s < e) ? csr_off[s] : make_float4(0.f, 0.f, 0.f, 0.f);
  for (int k = s; k < e; ++k) {
    const int d = d_next;
    const float4 o = o_next;
    if (k + 1 < e) { d_next = csr_dst[k + 1]; o_next = csr_off[k + 1]; }
    const float ht0 = Ht[(size_t)d * HID + g];
    const float ht1 = Ht[(size_t)d * HID + 64 + g];
    acc0 += o.x * ht0 + o.y * ht1;
    acc1 += o.z * ht0 + o.w * ht1;
  }
  const float4 dn = *(const float4*)(diag_n + n * 4);
  const float ht0 = Ht[(size_t)n * HID + g];
  const float ht1 = Ht[(size_t)n * HID + 64 + g];
  float lh0 = dn.x * ht0 + dn.y * ht1 + acc0;
  float lh1 = dn.z * ht0 + dn.w * ht1 + acc1;
  lh0 = (lh0 > 0.f) ? lh0 : (expf(lh0) - 1.f);
  lh1 = (lh1 > 0.f) ? lh1 : (expf(lh1) - 1.f);
  h[(size_t)n * HID + g]      -= lh0;
  h[(size_t)n * HID + 64 + g] -= lh1;
}

// ---- K7: out = MLP_out(h) [N,128]->relu64->40, LDS-tiled 64 nodes/block ----
__global__ __launch_bounds__(256) void k_mlp_out2(
    const float* __restrict__ h, const float* __restrict__ wf,
    const int* __restrict__ flag, void* __restrict__ outv)
{
  __shared__ float ht[64][132];
  float (*s_hid)[68] = (float(*)[68])&ht[0][0];   // overlay after layer1
  const int t = threadIdx.x;
  const int n0 = blockIdx.x * 64;
  {
    #pragma unroll
    for (int pp = 0; pp < 8; ++pp) {
      const int flat = pp * 256 + t;
      const int r = flat >> 5, c = (flat & 31) * 4;
      int node = n0 + r; if (node > N_NODES - 1) node = N_NODES - 1;
      *(float4*)&ht[r][c] = *(const float4*)(h + (size_t)node * HID + c);
    }
  }
  __syncthreads();
  float4 acc[4];
  const int jq = t & 15, nq = t >> 4;
  {
    #pragma unroll
    for (int i = 0; i < 4; ++i) acc[i] = make_float4(0.f, 0.f, 0.f, 0.f);
    for (int ks = 0; ks < 128; ks += 4) {
      float4 xr[4], wr[4];
      #pragma unroll
      for (int i = 0; i < 4; ++i) xr[i] = *(float4*)&ht[nq * 4 + i][ks];
      #pragma unroll
      for (int i = 0; i < 4; ++i)
        wr[i] = *(const float4*)(wf + OFF_WOUT1T + (ks + i) * 64 + jq * 4);
      #pragma unroll
      for (int i = 0; i < 4; ++i) {
        acc[i].x += xr[i].x*wr[0].x + xr[i].y*wr[1].x + xr[i].z*wr[2].x + xr[i].w*wr[3].x;
        acc[i].y += xr[i].x*wr[0].y + xr[i].y*wr[1].y + xr[i].z*wr[2].y + xr[i].w*wr[3].y;
        acc[i].z += xr[i].x*wr[0].z + xr[i].y*wr[1].z + xr[i].z*wr[2].z + xr[i].w*wr[3].z;
        acc[i].w += xr[i].x*wr[0].w + xr[i].y*wr[1].w + xr[i].z*wr[2].w + xr[i].w*wr[3].w;
      }
    }
  }
  __syncthreads();
  {
    float4 b1v = *(const float4*)(wf + OFF_BOUT1 + jq * 4);
    #pragma unroll
    for (int i = 0; i < 4; ++i) {
      float4 v;
      v.x = fmaxf(acc[i].x + b1v.x, 0.f);
      v.y = fmaxf(acc[i].y + b1v.y, 0.f);
      v.z = fmaxf(acc[i].z + b1v.z, 0.f);
      v.w = fmaxf(acc[i].w + b1v.w, 0.f);
      *(float4*)&s_hid[nq * 4 + i][jq * 4] = v;
    }
  }
  __syncthreads();
  const int bf = *flag;
  #pragma unroll
  for (int pp = 0; pp < 10; ++pp) {
    const int flat = pp * 256 + t;
    const int nl = flat / 40, o = flat - nl * 40;
    float acc2 = wf[OFF_BOUT2 + o];
    const float* wr = wf + OFF_WOUT2 + o * 64;
    #pragma unroll
    for (int j = 0; j < 64; j += 4) {
      float4 wv = *(const float4*)(wr + j);
      acc2 += s_hid[nl][j]*wv.x + s_hid[nl][j+1]*wv.y
            + s_hid[nl][j+2]*wv.z + s_hid[nl][j+3]*wv.w;
    }
    const int node = n0 + nl;
    if (node < N_NODES) {
      const int idx = node * OUTC + o;
      if (bf) ((u16*)outv)[idx] = f2bf(acc2);
      else    ((float*)outv)[idx] = acc2;
    }
  }
}

extern "C" void kernel_launch(void* const* d_in, const int* in_sizes, int n_in,
                              void* d_out, int out_size, void* d_ws, size_t ws_size,
                              hipStream_t stream)
{
  const int* ei = (const int*)d_in[1];

  float* ws   = (float*)d_ws;
  float* wf   = ws;                               // [0, 150644)
  const u16* bswh = (const u16*)(ws + OFF_BSWH);  // [150656, 167040)
  const u16* bswl = (const u16*)(ws + OFF_BSWL);  // [167040, 183424)
  int*   flag = (int*)(ws + 183424);
  float* h      = ws + 183440;                    // 2,560,000
  float* Ht     = h + 2560000;                    // 2,560,000
  float* csr_offv = Ht + 2560000;                 // 1,280,000 (float4[E_DIR])
  float* Dinv   = csr_offv + 1280000;             // 80,000
  float* diag_n = Dinv + 80000;                   // 80,000
  float* X      = diag_n + 80000;                 // maps + CSR index arrays
  float* maps   = X;                              // 1,280,000 floats (CSR order)
  int*   csr_dst = (int*)(X + 1280000);           // 320,000
  int*   csr_eid = (int*)(X + 1600000);           // 320,000
  int*   eslot   = (int*)(X + 1920000);           // 320,000
  int*   offsets = (int*)(X + 2240000);           // 20,001
  int*   cursor  = (int*)(X + 2260002);           // 20,000
  int*   deg     = (int*)(X + 2280002);           // 20,000
  u16*   u_s16   = (u16*)Ht;                      // alias (dead until k_ht)
  u16*   u_d16   = (u16*)Ht + 1280000;
  float4* csr_off = (float4*)csr_offv;

  P16 P;
  for (int i = 0; i < 16; ++i) P.p[i] = d_in[2 + i];

  k_sniff<<<1, 256, 0, stream>>>((const u16*)d_in[0], flag);
  k_convert<<<(WTOTAL + TTOTAL + 2 * BSW_N + 255) / 256, 256, 0, stream>>>(P, flag, wf);
  hipMemsetAsync(deg, 0, 20000 * sizeof(int), stream);
  k_deg<<<E_DIR / 256, 256, 0, stream>>>(ei, deg);
  k_scan<<<1, 256, 0, stream>>>(deg, offsets, cursor);
  k_csr_build<<<E_DIR / 256, 256, 0, stream>>>(ei, cursor, csr_eid, eslot);
  k_mlp_in<<<(N_NODES + 63) / 64, 256, 0, stream>>>(d_in[0], flag, wf, bswh, bswl,
                                                    h, u_s16, u_d16);
  k_edge_maps_csr<<<E_DIR / 64, 256, 0, stream>>>(u_s16, u_d16, ei, csr_eid, wf, maps);
  k_ftf_norm<<<(N_NODES + 255) / 256, 256, 0, stream>>>(maps, offsets, Dinv, diag_n);
  k_offn2<<<E_DIR / 256, 256, 0, stream>>>(maps, ei, Dinv, eslot, csr_eid,
                                           csr_dst, csr_off);

  const int offW1s[2]  = {OFF_W1_0,  OFF_W1_1};
  const int offW2Ts[2] = {OFF_W2_0T, OFF_W2_1T};
  for (int l = 0; l < 2; ++l) {
    k_ht<<<N_NODES / 4, 256, 0, stream>>>(h, wf, offW1s[l], offW2Ts[l], Ht);
    k_msgs_fused<<<N_NODES / 4, 256, 0, stream>>>(offsets, csr_dst, csr_off,
                                                  diag_n, Ht, h);
  }
  k_mlp_out2<<<(N_NODES + 63) / 64, 256, 0, stream>>>(h, wf, flag, d_out);
}

// Round 13
// 467.460 us; speedup vs baseline: 1.0688x; 1.0688x over previous
//
#include <hip/hip_runtime.h>
#include <math.h>

#define N_NODES 20000
#define E_HALF  160000
#define E_DIR   320000
#define IN_C    512
#define HID     128
#define OUTC    40

typedef unsigned short u16;
typedef unsigned int   u32;
typedef __attribute__((ext_vector_type(8))) short short8;   // 8 bf16
typedef __attribute__((ext_vector_type(4))) float f32x4;

// f32 weight arena offsets (elements)
#define OFF_WIN1  0
#define OFF_BIN1  32768
#define OFF_WIN2  32832
#define OFF_BIN2  41024
#define OFF_WMAP1 41152
#define OFF_BMAP1 57536
#define OFF_WMAP2 57600
#define OFF_BMAP2 57856
#define OFF_WOUT1 57860
#define OFF_BOUT1 66052
#define OFF_WOUT2 66116
#define OFF_BOUT2 68676
#define OFF_W1_0  68716
#define OFF_W2_0  68720
#define OFF_W1_1  72816
#define OFF_W2_1  72820
#define WTOTAL    76916
// transposed (k-major) copies
#define OFF_W1T     76916
#define OFF_WIN2T   109684
#define OFF_WMAP1AT 117876
#define OFF_WMAP1BT 126068
#define OFF_W2_0T   134260
#define OFF_W2_1T   138356
#define OFF_WOUT1T  142452
#define TTOTAL      73728
// MFMA B-fragment swizzled w_in1 hi/lo (u16 each, BSW_N entries)
#define OFF_BSWH  150656
#define OFF_BSWL  167040
#define BSW_N     32768

__device__ __forceinline__ float bfu2f(u16 u) {
  union { u32 i; float f; } v; v.i = ((u32)u) << 16; return v.f;
}
__device__ __forceinline__ u16 f2bf(float f) {
  union { float f; u32 u; } v; v.f = f;
  u32 u = v.u;
  u += 0x7fffu + ((u >> 16) & 1u);   // RNE
  return (u16)(u >> 16);
}

// ---- K0: sniff input float dtype. flag=1 -> bf16, flag=0 -> f32 ------------
__global__ void k_sniff(const u16* __restrict__ xv, int* __restrict__ flag) {
  __shared__ int s_bad;
  if (threadIdx.x == 0) s_bad = 0;
  __syncthreads();
  int bad = 0;
  for (int i = threadIdx.x; i < 2048; i += 256) {
    u16 u = xv[i];
    u32 ex = (u >> 7) & 0xFFu;
    if (!(ex >= 100 && ex <= 140) && (u & 0x7FFFu) != 0) bad++;
  }
  atomicAdd(&s_bad, bad);
  __syncthreads();
  if (threadIdx.x == 0) *flag = (s_bad < 64) ? 1 : 0;
}

// ---- K0b: convert weights + k-major transposes + MFMA B-swizzle hi/lo ------
struct P16 { const void* p[16]; };
__device__ __forceinline__ float rd_src(const void* p, int idx, int bf) {
  if (bf) return bfu2f(((const u16*)p)[idx]);
  return ((const float*)p)[idx];
}
__global__ __launch_bounds__(256) void k_convert(P16 s, const int* __restrict__ flag,
                                                 float* __restrict__ dst) {
  const int offs[17] = {OFF_WIN1, OFF_BIN1, OFF_WIN2, OFF_BIN2, OFF_WMAP1,
                        OFF_BMAP1, OFF_WMAP2, OFF_BMAP2, OFF_WOUT1, OFF_BOUT1,
                        OFF_WOUT2, OFF_BOUT2, OFF_W1_0, OFF_W2_0, OFF_W1_1,
                        OFF_W2_1, WTOTAL};
  const int i = blockIdx.x * 256 + threadIdx.x;
  const int bf = *flag;
  if (i < WTOTAL) {
    int sg = 0;
    #pragma unroll
    for (int k = 1; k < 16; ++k) if (i >= offs[k]) sg = k;
    dst[i] = rd_src(s.p[sg], i - offs[sg], bf);
    return;
  }
  if (i < WTOTAL + TTOTAL) {
    const int it = i - WTOTAL;
    // {dst_off, Pidx, J, src_stride, size, colofs}
    const int tab[7][6] = {
      {OFF_W1T,      0, 64, 512, 32768,   0},
      {OFF_WIN2T,    2, 128, 64,  8192,   0},
      {OFF_WMAP1AT,  4, 64, 256,  8192,   0},
      {OFF_WMAP1BT,  4, 64, 256,  8192, 128},
      {OFF_W2_0T,   13, 64,  64,  4096,   0},
      {OFF_W2_1T,   15, 64,  64,  4096,   0},
      {OFF_WOUT1T,   8, 64, 128,  8192,   0}};
    int sg = 0, base = 0;
    #pragma unroll
    for (int t = 0; t < 7; ++t) {
      if (it >= base && it < base + tab[t][4]) { sg = t; break; }
      base += tab[t][4];
    }
    const int local = it - base;
    const int J = tab[sg][2];
    const int k = local / J, j = local - k * J;
    dst[tab[sg][0] + local] =
        rd_src(s.p[tab[sg][1]], j * tab[sg][3] + k + tab[sg][5], bf);
    return;
  }
  const int ib = i - (WTOTAL + TTOTAL);
  if (ib >= 2 * BSW_N) return;
  const int which = ib >> 15;                 // 0 = hi, 1 = lo
  const int ic = ib & (BSW_N - 1);
  // B-fragment swizzle of w_in1 for mfma_f32_16x16x32_bf16:
  // lane l holds B[k=(l>>4)*8+j][n=l&15]; buffer idx ((kc*4+nt)*64+l)*8+j
  const int j = ic & 7, l = (ic >> 3) & 63, nt = (ic >> 9) & 3, kc = ic >> 11;
  const int col = nt * 16 + (l & 15);         // output channel (0..63)
  const int kk = kc * 32 + (l >> 4) * 8 + j;  // k index (0..511)
  u16 outv;
  if (bf) {
    u16 wv = ((const u16*)s.p[0])[col * 512 + kk];
    outv = which ? (u16)0 : wv;
  } else {
    float wv = ((const float*)s.p[0])[col * 512 + kk];
    u16 hi = f2bf(wv);
    if (which == 0) outv = hi;
    else            outv = f2bf(wv - bfu2f(hi));
  }
  ((u16*)(dst + (which ? OFF_BSWL : OFF_BSWH)))[ic] = outv;
}

// ---- K0c: degree histogram (needs only ei) ---------------------------------
__global__ __launch_bounds__(256) void k_deg(const int* __restrict__ ei,
                                             int* __restrict__ deg) {
  const int e = blockIdx.x * 256 + threadIdx.x;
  if (e < E_DIR) atomicAdd(&deg[ei[e]], 1);
}

// ---- K0d: scan phase 1 — per-chunk sums (79 blocks, coalesced) -------------
__global__ __launch_bounds__(256) void k_scan1(const int* __restrict__ deg,
                                               int* __restrict__ csum) {
  __shared__ int s[256];
  const int t = threadIdx.x;
  const int idx = blockIdx.x * 256 + t;
  s[t] = (idx < N_NODES) ? deg[idx] : 0;
  __syncthreads();
  for (int off = 128; off > 0; off >>= 1) {
    if (t < off) s[t] += s[t + off];
    __syncthreads();
  }
  if (t == 0) csum[blockIdx.x] = s[0];
}

// ---- K0e: scan phase 2 — block base + local scan, write offsets/cursor -----
__global__ __launch_bounds__(256) void k_scan2(
    const int* __restrict__ deg, const int* __restrict__ csum,
    int* __restrict__ offsets, int* __restrict__ cursor) {
  __shared__ int s[256];
  const int t = threadIdx.x;
  const int b = blockIdx.x;
  s[t] = (t < b) ? csum[t] : 0;     // b <= 78 < 256
  __syncthreads();
  for (int off = 128; off > 0; off >>= 1) {
    if (t < off) s[t] += s[t + off];
    __syncthreads();
  }
  const int base = s[0];
  __syncthreads();
  const int idx = b * 256 + t;
  const int d = (idx < N_NODES) ? deg[idx] : 0;
  s[t] = d;
  __syncthreads();
  for (int off = 1; off < 256; off <<= 1) {
    int tmp = (t >= off) ? s[t - off] : 0;
    __syncthreads();
    s[t] += tmp;
    __syncthreads();
  }
  const int excl = s[t] - d + base;
  if (idx < N_NODES) { offsets[idx] = excl; cursor[idx] = excl; }
  if (idx == N_NODES - 1) offsets[N_NODES] = E_DIR;
}

// ---- K1: h = MLP_in(x) + fused u_s/u_d (bf16 out). 8 nodes/wave MFMA -------
// 2500 independent waves (625 blocks) for latency hiding; no barriers.
__global__ __launch_bounds__(256) void k_mlp_in(
    const void* __restrict__ xv, const int* __restrict__ flag,
    const float* __restrict__ wf, const u16* __restrict__ bswh,
    const u16* __restrict__ bswl,
    float* __restrict__ h, u16* __restrict__ u_s16, u16* __restrict__ u_d16)
{
  __shared__ float smem[6400];                // 4 waves x 1600 floats
  const int t = threadIdx.x;
  const int w = t >> 6, l = t & 63;
  const int nw = blockIdx.x * 32 + w * 8;     // wave's node base (8 nodes)
  if (nw >= N_NODES) return;                  // wave-uniform (N % 8 == 0)
  const int bf = *flag;
  const int m = l & 15, q = l >> 4;
  float* wbase = smem + w * 1600;
  float (*sh)[68]   = (float(*)[68])wbase;            // 8 x 68
  float (*hti)[132] = (float(*)[132])(wbase + 544);   // 8 x 132

  // ---- layer1: [8x512] @ [512x64] via MFMA (rows 8..15 duplicate) ---------
  {
    const int node = nw + (m & 7);
    f32x4 acc0 = {0.f,0.f,0.f,0.f}, acc1 = acc0, acc2 = acc0, acc3 = acc0;
    for (int kc = 0; kc < 16; ++kc) {
      short8 Ahi = (short8)0, Alo = (short8)0;
      if (bf) {
        Ahi = *(const short8*)((const u16*)xv + (size_t)node * IN_C + kc * 32 + q * 8);
      } else {
        const float* xr = (const float*)xv + (size_t)node * IN_C + kc * 32 + q * 8;
        float4 xa = *(const float4*)xr;
        float4 xb = *(const float4*)(xr + 4);
        float xf[8] = {xa.x, xa.y, xa.z, xa.w, xb.x, xb.y, xb.z, xb.w};
        #pragma unroll
        for (int j = 0; j < 8; ++j) {
          u16 hi = f2bf(xf[j]);
          union { float f; u32 u; } rv; rv.f = xf[j] - bfu2f(hi);
          Ahi[j] = (short)hi;
          Alo[j] = (short)(rv.u >> 16);       // trunc bf16 of residual
        }
      }
      const u16* bh = bswh + (size_t)(kc * 4) * 512 + l * 8;
      short8 B0 = *(const short8*)(bh);
      short8 B1 = *(const short8*)(bh + 512);
      short8 B2 = *(const short8*)(bh + 1024);
      short8 B3 = *(const short8*)(bh + 1536);
      if (!bf) {
        const u16* bl = bswl + (size_t)(kc * 4) * 512 + l * 8;
        short8 L0 = *(const short8*)(bl);
        short8 L1 = *(const short8*)(bl + 512);
        short8 L2 = *(const short8*)(bl + 1024);
        short8 L3 = *(const short8*)(bl + 1536);
        acc0 = __builtin_amdgcn_mfma_f32_16x16x32_bf16(Alo, B0, acc0, 0, 0, 0);
        acc1 = __builtin_amdgcn_mfma_f32_16x16x32_bf16(Alo, B1, acc1, 0, 0, 0);
        acc2 = __builtin_amdgcn_mfma_f32_16x16x32_bf16(Alo, B2, acc2, 0, 0, 0);
        acc3 = __builtin_amdgcn_mfma_f32_16x16x32_bf16(Alo, B3, acc3, 0, 0, 0);
        acc0 = __builtin_amdgcn_mfma_f32_16x16x32_bf16(Ahi, L0, acc0, 0, 0, 0);
        acc1 = __builtin_amdgcn_mfma_f32_16x16x32_bf16(Ahi, L1, acc1, 0, 0, 0);
        acc2 = __builtin_amdgcn_mfma_f32_16x16x32_bf16(Ahi, L2, acc2, 0, 0, 0);
        acc3 = __builtin_amdgcn_mfma_f32_16x16x32_bf16(Ahi, L3, acc3, 0, 0, 0);
      }
      acc0 = __builtin_amdgcn_mfma_f32_16x16x32_bf16(Ahi, B0, acc0, 0, 0, 0);
      acc1 = __builtin_amdgcn_mfma_f32_16x16x32_bf16(Ahi, B1, acc1, 0, 0, 0);
      acc2 = __builtin_amdgcn_mfma_f32_16x16x32_bf16(Ahi, B2, acc2, 0, 0, 0);
      acc3 = __builtin_amdgcn_mfma_f32_16x16x32_bf16(Ahi, B3, acc3, 0, 0, 0);
    }
    // D: lane holds D[row=q*4+r][col=m] per n-tile; rows 0..7 are real nodes
    f32x4 av[4] = {acc0, acc1, acc2, acc3};
    if (q < 2) {
      #pragma unroll
      for (int nt = 0; nt < 4; ++nt) {
        const int j = nt * 16 + m;
        const float bj = wf[OFF_BIN1 + j];
        #pragma unroll
        for (int r = 0; r < 4; ++r)
          sh[q * 4 + r][j] = fmaxf(av[nt][r] + bj, 0.f);
      }
    }
  }
  // ---- layer2: [8x64] @ [64x128] f32 VALU; lanes: 2 nodes x 8 outputs -----
  {
    const int ngrp = l >> 4, og = (l & 15) * 8;   // ngrp in 0..3, 2 nodes each
    f32x4 a2a[2], a2b[2];
    #pragma unroll
    for (int i = 0; i < 2; ++i) { a2a[i] = (f32x4){0.f,0.f,0.f,0.f}; a2b[i] = a2a[i]; }
    for (int k = 0; k < 64; k += 4) {
      f32x4 sv[2], w0[4], w1[4];
      #pragma unroll
      for (int i = 0; i < 2; ++i) sv[i] = *(f32x4*)&sh[ngrp * 2 + i][k];
      #pragma unroll
      for (int kk = 0; kk < 4; ++kk) {
        const float* wr = wf + OFF_WIN2T + (k + kk) * 128 + og;
        w0[kk] = *(const f32x4*)wr;
        w1[kk] = *(const f32x4*)(wr + 4);
      }
      #pragma unroll
      for (int i = 0; i < 2; ++i) {
        #pragma unroll
        for (int kk = 0; kk < 4; ++kk) {
          a2a[i] += sv[i][kk] * w0[kk];
          a2b[i] += sv[i][kk] * w1[kk];
        }
      }
    }
    f32x4 b2a = *(const f32x4*)(wf + OFF_BIN2 + og);
    f32x4 b2b = *(const f32x4*)(wf + OFF_BIN2 + og + 4);
    #pragma unroll
    for (int i = 0; i < 2; ++i) {
      a2a[i] += b2a; a2b[i] += b2b;
      const int node = nw + ngrp * 2 + i;
      *(f32x4*)&h[(size_t)node * HID + og]     = a2a[i];
      *(f32x4*)&h[(size_t)node * HID + og + 4] = a2b[i];
      *(f32x4*)&hti[ngrp * 2 + i][og]     = a2a[i];
      *(f32x4*)&hti[ngrp * 2 + i][og + 4] = a2b[i];
    }
  }
  // ---- u-projection: [8x128] @ [128x64] x2 -> bf16 stores -----------------
  {
    const int ngrp = l >> 4, ug = (l & 15) * 4;
    f32x4 us[2], ud[2];
    #pragma unroll
    for (int i = 0; i < 2; ++i) { us[i] = (f32x4){0.f,0.f,0.f,0.f}; ud[i] = us[i]; }
    for (int k = 0; k < 128; k += 4) {
      f32x4 av[2], wsv[4], wdv[4];
      #pragma unroll
      for (int i = 0; i < 2; ++i) av[i] = *(f32x4*)&hti[ngrp * 2 + i][k];
      #pragma unroll
      for (int kk = 0; kk < 4; ++kk) {
        wsv[kk] = *(const f32x4*)(wf + OFF_WMAP1AT + (k + kk) * 64 + ug);
        wdv[kk] = *(const f32x4*)(wf + OFF_WMAP1BT + (k + kk) * 64 + ug);
      }
      #pragma unroll
      for (int i = 0; i < 2; ++i) {
        #pragma unroll
        for (int kk = 0; kk < 4; ++kk) {
          us[i] += av[i][kk] * wsv[kk];
          ud[i] += av[i][kk] * wdv[kk];
        }
      }
    }
    #pragma unroll
    for (int i = 0; i < 2; ++i) {
      const int node = nw + ngrp * 2 + i;
      ushort4 os, od;
      os.x = f2bf(us[i][0]); os.y = f2bf(us[i][1]);
      os.z = f2bf(us[i][2]); os.w = f2bf(us[i][3]);
      od.x = f2bf(ud[i][0]); od.y = f2bf(ud[i][1]);
      od.z = f2bf(ud[i][2]); od.w = f2bf(ud[i][3]);
      *(ushort4*)&u_s16[(size_t)node * 64 + ug] = os;
      *(ushort4*)&u_d16[(size_t)node * 64 + ug] = od;
    }
  }
}

// ---- K2: edge maps, CSR-ordered; maps written in CSR slot order ------------
__global__ __launch_bounds__(256) void k_edge_maps_csr(
    const u16* __restrict__ u_s16, const u16* __restrict__ u_d16,
    const int* __restrict__ ei, const int* __restrict__ csr_eid,
    const float* __restrict__ wf, float* __restrict__ maps)
{
  __shared__ float s_act[64][68];
  const int t = threadIdx.x;
  const int w = t >> 6, l = t & 63;
  const int p0 = blockIdx.x * 64;
  const float bias = wf[OFF_BMAP1 + l];
  const int pb = p0 + w * 16;
  #pragma unroll 4
  for (int i = 0; i < 16; ++i) {
    const int e = csr_eid[pb + i];
    const int sn = ei[e], dn = ei[E_DIR + e];
    float v = bfu2f(u_s16[(size_t)sn * 64 + l]) +
              bfu2f(u_d16[(size_t)dn * 64 + l]) + bias;
    s_act[w * 16 + i][l] = fmaxf(v, 0.f);
  }
  __syncthreads();
  const int ee = t >> 2, ko = t & 3;
  float acc = wf[OFF_BMAP2 + ko];
  const float* wr = wf + OFF_WMAP2 + ko * 64;
  #pragma unroll
  for (int j = 0; j < 64; j += 4) {
    float4 wv = *(const float4*)(wr + j);
    float4 av = *(const float4*)(&s_act[ee][j]);
    acc += av.x*wv.x + av.y*wv.y + av.z*wv.z + av.w*wv.w;
  }
  maps[(p0 + ee) * 4 + ko] = acc;
}

// ---- K4c: bucket edges by src; record slot of each edge --------------------
__global__ __launch_bounds__(256) void k_csr_build(
    const int* __restrict__ ei, int* __restrict__ cursor,
    int* __restrict__ csr_eid, int* __restrict__ eslot)
{
  const int e = blockIdx.x * 256 + threadIdx.x;
  if (e >= E_DIR) return;
  const int sn = ei[e];
  const int pos = atomicAdd(&cursor[sn], 1);
  csr_eid[pos] = e;
  eslot[e] = pos;
}

// ---- K4d: per-node FtF gather (sequential CSR maps) + 2x2 eig --------------
__global__ __launch_bounds__(256) void k_ftf_norm(
    const float* __restrict__ maps, const int* __restrict__ offsets,
    float* __restrict__ Dinv, float* __restrict__ diag_n)
{
  const int n = blockIdx.x * 256 + threadIdx.x;
  if (n >= N_NODES) return;
  const int s = offsets[n], e = offsets[n + 1];
  float a = 0.f, b = 0.f, c = 0.f;
  for (int p = s; p < e; ++p) {
    float4 m = *(const float4*)(maps + (size_t)p * 4);
    a += m.x * m.x + m.z * m.z;
    b += m.x * m.y + m.z * m.w;
    c += m.y * m.y + m.w * m.w;
  }
  float mean = 0.5f * (a + c), diff = 0.5f * (a - c);
  float rad = sqrtf(diff * diff + b * b);
  float l1 = mean - rad, l2 = mean + rad;
  float s1 = 1.0f / sqrtf(fmaxf(l1, 1e-6f));
  float s2 = 1.0f / sqrtf(fmaxf(l2, 1e-6f));
  float D00, D01, D11;
  if (rad < 1e-20f) {
    float s0 = 1.0f / sqrtf(fmaxf(mean, 1e-6f));
    D00 = s0; D01 = 0.f; D11 = s0;
  } else {
    float vx, vy;
    if (diff >= 0.f) { vx = rad + diff; vy = b; }
    else             { vx = b;          vy = rad - diff; }
    float inv = 1.0f / sqrtf(vx * vx + vy * vy);
    float ux = vx * inv, uy = vy * inv;
    D00 = s1 * uy * uy + s2 * ux * ux;
    D01 = (s2 - s1) * ux * uy;
    D11 = s1 * ux * ux + s2 * uy * uy;
  }
  Dinv[n * 4 + 0] = D00; Dinv[n * 4 + 1] = D01;
  Dinv[n * 4 + 2] = D01; Dinv[n * 4 + 3] = D11;
  float t00 = D00 * a + D01 * b, t01 = D00 * b + D01 * c;
  float t10 = D01 * a + D11 * b, t11 = D01 * b + D11 * c;
  diag_n[n * 4 + 0] = t00 * D00 + t01 * D01;
  diag_n[n * 4 + 1] = t00 * D01 + t01 * D11;
  diag_n[n * 4 + 2] = t10 * D00 + t11 * D01;
  diag_n[n * 4 + 3] = t10 * D01 + t11 * D11;
}

// ---- K5: off_n per CSR position (coalesced maps/csr writes) ----------------
__global__ void k_offn2(const float* __restrict__ maps, const int* __restrict__ ei,
                        const float* __restrict__ Dinv, const int* __restrict__ eslot,
                        const int* __restrict__ csr_eid,
                        int* __restrict__ csr_dst, float4* __restrict__ csr_off)
{
  const int pos = blockIdx.x * 256 + threadIdx.x;
  if (pos >= E_DIR) return;
  const int e = csr_eid[pos];
  const int r = (e < E_HALF) ? (e + E_HALF) : (e - E_HALF);
  const int rpos = eslot[r];
  float4 me = *(const float4*)(maps + (size_t)pos * 4);
  float4 mr = *(const float4*)(maps + (size_t)rpos * 4);
  float o00 = -(me.x * mr.x + me.z * mr.z);
  float o01 = -(me.x * mr.y + me.z * mr.w);
  float o10 = -(me.y * mr.x + me.w * mr.z);
  float o11 = -(me.y * mr.y + me.w * mr.w);
  const int sn = ei[e], dn = ei[E_DIR + e];
  float4 Ds = *(const float4*)(Dinv + sn * 4);
  float4 Dd = *(const float4*)(Dinv + dn * 4);
  float t00 = Ds.x * o00 + Ds.y * o10;
  float t01 = Ds.x * o01 + Ds.y * o11;
  float t10 = Ds.z * o00 + Ds.w * o10;
  float t11 = Ds.z * o01 + Ds.w * o11;
  float4 q;
  q.x = t00 * Dd.x + t01 * Dd.z;
  q.y = t00 * Dd.y + t01 * Dd.w;
  q.z = t10 * Dd.x + t11 * Dd.z;
  q.w = t10 * Dd.y + t11 * Dd.w;
  csr_dst[pos] = dn;
  csr_off[pos] = q;
}

// ---- K6a: Ht = W1^T (h3 @ W2^T) per node -----------------------------------
__global__ __launch_bounds__(256) void k_ht(
    const float* __restrict__ h, const float* __restrict__ wf,
    int offW1, int offW2T, float* __restrict__ Ht)
{
  const int t = threadIdx.x;
  const int n = blockIdx.x * 4 + (t >> 6);
  const int g = t & 63;
  const float w1_00 = wf[offW1 + 0], w1_01 = wf[offW1 + 1];
  const float w1_10 = wf[offW1 + 2], w1_11 = wf[offW1 + 3];
  float acc0 = 0.f, acc1 = 0.f;
  const float* wt = wf + offW2T + g;
  const float* h0 = h + (size_t)n * HID;
  #pragma unroll 4
  for (int kk = 0; kk < 64; kk += 4) {
    float4 p0 = *(const float4*)(h0 + kk);
    float4 p1 = *(const float4*)(h0 + 64 + kk);
    const float* w0 = wt + kk * 64;
    float wv0 = w0[0], wv1 = w0[64], wv2 = w0[128], wv3 = w0[192];
    acc0 += p0.x*wv0 + p0.y*wv1 + p0.z*wv2 + p0.w*wv3;
    acc1 += p1.x*wv0 + p1.y*wv1 + p1.z*wv2 + p1.w*wv3;
  }
  Ht[n * HID + g]      = w1_00 * acc0 + w1_10 * acc1;
  Ht[n * HID + 64 + g] = w1_01 * acc0 + w1_11 * acc1;
}

// ---- K6b: per-node gather msgs + diag term + ELU + h update (fused) --------
__global__ __launch_bounds__(256) void k_msgs_fused(
    const int* __restrict__ offsets, const int* __restrict__ csr_dst,
    const float4* __restrict__ csr_off, const float* __restrict__ diag_n,
    const float* __restrict__ Ht, float* __restrict__ h)
{
  const int n = blockIdx.x * 4 + (threadIdx.x >> 6);
  const int g = threadIdx.x & 63;
  const int s = offsets[n], e = offsets[n + 1];
  float acc0 = 0.f, acc1 = 0.f;
  int d_next = (s < e) ? csr_dst[s] : 0;
  float4 o_next = (s < e) ? csr_off[s] : make_float4(0.f, 0.f, 0.f, 0.f);
  for (int k = s; k < e; ++k) {
    const int d = d_next;
    const float4 o = o_next;
    if (k + 1 < e) { d_next = csr_dst[k + 1]; o_next = csr_off[k + 1]; }
    const float ht0 = Ht[(size_t)d * HID + g];
    const float ht1 = Ht[(size_t)d * HID + 64 + g];
    acc0 += o.x * ht0 + o.y * ht1;
    acc1 += o.z * ht0 + o.w * ht1;
  }
  const float4 dn = *(const float4*)(diag_n + n * 4);
  const float ht0 = Ht[(size_t)n * HID + g];
  const float ht1 = Ht[(size_t)n * HID + 64 + g];
  float lh0 = dn.x * ht0 + dn.y * ht1 + acc0;
  float lh1 = dn.z * ht0 + dn.w * ht1 + acc1;
  lh0 = (lh0 > 0.f) ? lh0 : (expf(lh0) - 1.f);
  lh1 = (lh1 > 0.f) ? lh1 : (expf(lh1) - 1.f);
  h[(size_t)n * HID + g]      -= lh0;
  h[(size_t)n * HID + 64 + g] -= lh1;
}

// ---- K7: out = MLP_out(h) [N,128]->relu64->40, LDS-tiled 64 nodes/block ----
__global__ __launch_bounds__(256) void k_mlp_out2(
    const float* __restrict__ h, const float* __restrict__ wf,
    const int* __restrict__ flag, void* __restrict__ outv)
{
  __shared__ float ht[64][132];
  float (*s_hid)[68] = (float(*)[68])&ht[0][0];   // overlay after layer1
  const int t = threadIdx.x;
  const int n0 = blockIdx.x * 64;
  {
    #pragma unroll
    for (int pp = 0; pp < 8; ++pp) {
      const int flat = pp * 256 + t;
      const int r = flat >> 5, c = (flat & 31) * 4;
      int node = n0 + r; if (node > N_NODES - 1) node = N_NODES - 1;
      *(float4*)&ht[r][c] = *(const float4*)(h + (size_t)node * HID + c);
    }
  }
  __syncthreads();
  float4 acc[4];
  const int jq = t & 15, nq = t >> 4;
  {
    #pragma unroll
    for (int i = 0; i < 4; ++i) acc[i] = make_float4(0.f, 0.f, 0.f, 0.f);
    for (int ks = 0; ks < 128; ks += 4) {
      float4 xr[4], wr[4];
      #pragma unroll
      for (int i = 0; i < 4; ++i) xr[i] = *(float4*)&ht[nq * 4 + i][ks];
      #pragma unroll
      for (int i = 0; i < 4; ++i)
        wr[i] = *(const float4*)(wf + OFF_WOUT1T + (ks + i) * 64 + jq * 4);
      #pragma unroll
      for (int i = 0; i < 4; ++i) {
        acc[i].x += xr[i].x*wr[0].x + xr[i].y*wr[1].x + xr[i].z*wr[2].x + xr[i].w*wr[3].x;
        acc[i].y += xr[i].x*wr[0].y + xr[i].y*wr[1].y + xr[i].z*wr[2].y + xr[i].w*wr[3].y;
        acc[i].z += xr[i].x*wr[0].z + xr[i].y*wr[1].z + xr[i].z*wr[2].z + xr[i].w*wr[3].z;
        acc[i].w += xr[i].x*wr[0].w + xr[i].y*wr[1].w + xr[i].z*wr[2].w + xr[i].w*wr[3].w;
      }
    }
  }
  __syncthreads();
  {
    float4 b1v = *(const float4*)(wf + OFF_BOUT1 + jq * 4);
    #pragma unroll
    for (int i = 0; i < 4; ++i) {
      float4 v;
      v.x = fmaxf(acc[i].x + b1v.x, 0.f);
      v.y = fmaxf(acc[i].y + b1v.y, 0.f);
      v.z = fmaxf(acc[i].z + b1v.z, 0.f);
      v.w = fmaxf(acc[i].w + b1v.w, 0.f);
      *(float4*)&s_hid[nq * 4 + i][jq * 4] = v;
    }
  }
  __syncthreads();
  const int bf = *flag;
  #pragma unroll
  for (int pp = 0; pp < 10; ++pp) {
    const int flat = pp * 256 + t;
    const int nl = flat / 40, o = flat - nl * 40;
    float acc2 = wf[OFF_BOUT2 + o];
    const float* wr = wf + OFF_WOUT2 + o * 64;
    #pragma unroll
    for (int j = 0; j < 64; j += 4) {
      float4 wv = *(const float4*)(wr + j);
      acc2 += s_hid[nl][j]*wv.x + s_hid[nl][j+1]*wv.y
            + s_hid[nl][j+2]*wv.z + s_hid[nl][j+3]*wv.w;
    }
    const int node = n0 + nl;
    if (node < N_NODES) {
      const int idx = node * OUTC + o;
      if (bf) ((u16*)outv)[idx] = f2bf(acc2);
      else    ((float*)outv)[idx] = acc2;
    }
  }
}

extern "C" void kernel_launch(void* const* d_in, const int* in_sizes, int n_in,
                              void* d_out, int out_size, void* d_ws, size_t ws_size,
                              hipStream_t stream)
{
  const int* ei = (const int*)d_in[1];

  float* ws   = (float*)d_ws;
  float* wf   = ws;                               // [0, 150644)
  const u16* bswh = (const u16*)(ws + OFF_BSWH);  // [150656, 167040)
  const u16* bswl = (const u16*)(ws + OFF_BSWL);  // [167040, 183424)
  int*   flag = (int*)(ws + 183424);
  float* h      = ws + 183440;                    // 2,560,000
  float* Ht     = h + 2560000;                    // 2,560,000
  float* csr_offv = Ht + 2560000;                 // 1,280,000 (float4[E_DIR])
  float* Dinv   = csr_offv + 1280000;             // 80,000
  float* diag_n = Dinv + 80000;                   // 80,000
  float* X      = diag_n + 80000;                 // maps + CSR index arrays
  float* maps   = X;                              // 1,280,000 floats (CSR order)
  int*   csr_dst = (int*)(X + 1280000);           // 320,000
  int*   csr_eid = (int*)(X + 1600000);           // 320,000
  int*   eslot   = (int*)(X + 1920000);           // 320,000
  int*   offsets = (int*)(X + 2240000);           // 20,001
  int*   cursor  = (int*)(X + 2260002);           // 20,000
  int*   deg     = (int*)(X + 2280002);           // 20,000
  int*   csum    = (int*)(X + 2300002);           // 79
  u16*   u_s16   = (u16*)Ht;                      // alias (dead until k_ht)
  u16*   u_d16   = (u16*)Ht + 1280000;
  float4* csr_off = (float4*)csr_offv;

  P16 P;
  for (int i = 0; i < 16; ++i) P.p[i] = d_in[2 + i];

  k_sniff<<<1, 256, 0, stream>>>((const u16*)d_in[0], flag);
  k_convert<<<(WTOTAL + TTOTAL + 2 * BSW_N + 255) / 256, 256, 0, stream>>>(P, flag, wf);
  hipMemsetAsync(deg, 0, 20000 * sizeof(int), stream);
  k_deg<<<E_DIR / 256, 256, 0, stream>>>(ei, deg);
  k_scan1<<<(N_NODES + 255) / 256, 256, 0, stream>>>(deg, csum);
  k_scan2<<<(N_NODES + 255) / 256, 256, 0, stream>>>(deg, csum, offsets, cursor);
  k_csr_build<<<E_DIR / 256, 256, 0, stream>>>(ei, cursor, csr_eid, eslot);
  k_mlp_in<<<(N_NODES + 31) / 32, 256, 0, stream>>>(d_in[0], flag, wf, bswh, bswl,
                                                    h, u_s16, u_d16);
  k_edge_maps_csr<<<E_DIR / 64, 256, 0, stream>>>(u_s16, u_d16, ei, csr_eid, wf, maps);
  k_ftf_norm<<<(N_NODES + 255) / 256, 256, 0, stream>>>(maps, offsets, Dinv, diag_n);
  k_offn2<<<E_DIR / 256, 256, 0, stream>>>(maps, ei, Dinv, eslot, csr_eid,
                                           csr_dst, csr_off);

  const int offW1s[2]  = {OFF_W1_0,  OFF_W1_1};
  const int offW2Ts[2] = {OFF_W2_0T, OFF_W2_1T};
  for (int l = 0; l < 2; ++l) {
    k_ht<<<N_NODES / 4, 256, 0, stream>>>(h, wf, offW1s[l], offW2Ts[l], Ht);
    k_msgs_fused<<<N_NODES / 4, 256, 0, stream>>>(offsets, csr_dst, csr_off,
                                                  diag_n, Ht, h);
  }
  k_mlp_out2<<<(N_NODES + 63) / 64, 256, 0, stream>>>(h, wf, flag, d_out);
}